// Round 11
// baseline (218.620 us; speedup 1.0000x reference)
//
#include <hip/hip_runtime.h>
#include <hip/hip_bf16.h>
#include <stdint.h>

#define THREADS 512            // 8 waves/block; 4 blocks/CU -> 32 waves/CU
#define PTHREADS 256
#define ROWS_PER_BLOCK 8
#define JSPLIT 2
#define EMB_ROWS 5050
#define PACK_OFF 65536   // byte offset of packed float4 array in d_ws

typedef _Float16 half2v __attribute__((ext_vector_type(2)));
typedef __fp16   fp16x2 __attribute__((ext_vector_type(2)));

__device__ __forceinline__ half2v pk(float a, float b) {
    fp16x2 r = __builtin_amdgcn_cvt_pkrtz(a, b);   // v_cvt_pkrtz_f16_f32
    return __builtin_bit_cast(half2v, r);
}
__device__ __forceinline__ half2v pkfma(half2v a, half2v b, half2v c) {
    return __builtin_elementwise_fma(a, b, c);     // v_pk_fma_f16
}

__global__ __launch_bounds__(PTHREADS) void pack_kernel(
    const float* __restrict__ coords, const float* __restrict__ charges,
    float4* __restrict__ pack, int n)
{
    const int i = blockIdx.x * PTHREADS + threadIdx.x;
    if (i < n)
        pack[i] = make_float4(coords[3 * i], coords[3 * i + 1],
                              coords[3 * i + 2], charges[i]);
}

// Each block: 8 rows (i) x a 2048-wide slice of columns (j), 512 threads.
// Latency-bound fix: 8 waves/SIMD resident (grid 1024 x 8 waves, VGPR<=64)
// so ~4-cyc dependent-chain stalls are covered by other waves.
__global__ __launch_bounds__(THREADS, 8) void energy_main_kernel(
    const float4* __restrict__ pack,
    const int*    __restrict__ atom_ix,
    const float*  __restrict__ emb,
    const float*  __restrict__ W1,
    const float*  __restrict__ b1,
    const float*  __restrict__ W2,
    const float*  __restrict__ b2,
    float* __restrict__ partials,
    int n_atoms)
{
    __shared__ uint32_t s_emb2[EMB_ROWS];
    for (int t = threadIdx.x; t < EMB_ROWS; t += THREADS) {
        const float e = emb[t];
        s_emb2[t] = __builtin_bit_cast(uint32_t, pk(e, e));
    }

    // k-packed weights; wave-uniform -> compiler places in SGPRs.
    half2v A2[8], B2[8], C2[8], U0_2[8], U1_2[8], U2_2[8];
#pragma unroll
    for (int p = 0; p < 8; ++p) {
        A2[p]   = pk(W1[2 * p],      W1[2 * p + 1]);        // W1[0][k]
        B2[p]   = pk(W1[16 + 2 * p], W1[16 + 2 * p + 1]);   // W1[1][k]
        C2[p]   = pk(b1[2 * p],      b1[2 * p + 1]);
        U0_2[p] = pk(W2[3 * (2 * p) + 0], W2[3 * (2 * p + 1) + 0]);
        U1_2[p] = pk(W2[3 * (2 * p) + 1], W2[3 * (2 * p + 1) + 1]);
        U2_2[p] = pk(W2[3 * (2 * p) + 2], W2[3 * (2 * p + 1) + 2]);
    }
    const float bo0 = b2[0], bo1 = b2[1], bo2 = b2[2];

    const int rb   = blockIdx.x / JSPLIT;
    const int js   = blockIdx.x % JSPLIT;
    const int row0 = rb * ROWS_PER_BLOCK;
    const int jlen = n_atoms / JSPLIT;
    const int j0   = js * jlen;
    const int jend = j0 + jlen;

    float  xr[ROWS_PER_BLOCK], yr[ROWS_PER_BLOCK], zr[ROWS_PER_BLOCK];
    half2v qr2[ROWS_PER_BLOCK];
    int    brb4[ROWS_PER_BLOCK];   // emb row base, BYTE offset
#pragma unroll
    for (int r = 0; r < ROWS_PER_BLOCK; ++r) {
        const int i = row0 + r;
        const float4 p = pack[i];
        xr[r] = p.x; yr[r] = p.y; zr[r] = p.z;
        qr2[r] = pk(p.w, p.w);
        const int a = atom_ix[i];
        brb4[r] = ((a * (a + 1)) >> 1) << 2;
    }
    __syncthreads();

    float cacc = 0.0f, ljacc = 0.0f;
    const half2v zero2 = (half2v)(_Float16)0.0f;
    const char* sbase = (const char*)s_emb2;

#pragma unroll 1
    for (int j = j0 + threadIdx.x; j < jend; j += THREADS) {
        const float4 pj = pack[j];
        const int    aj = atom_ix[j];
        const half2v qj2 = pk(pj.w, pj.w);
        const int    ajb = aj << 2;

#pragma unroll
        for (int r = 0; r < ROWS_PER_BLOCK; ++r) {
            const float dx = pj.x - xr[r];
            const float dy = pj.y - yr[r];
            const float dz = pj.z - zr[r];
            const float sq = fmaf(dx, dx, fmaf(dy, dy, dz * dz));
            // sq==0 (diagonal): v_rsq_f32(0)=+inf, fminf(inf,10)=10 -> matches
            // the reference's nan_to_num + clamp-to-10 semantics exactly.
            const float rd = fminf(__builtin_amdgcn_rsqf(sq), 10.0f);

            const half2v e2 = *(const half2v*)(sbase + brb4[r] + ajb);
            const half2v c2 = qr2[r] * qj2;               // v_pk_mul_f16

            float o0 = bo0, o1 = bo1, o2 = bo2;
#pragma unroll
            for (int p = 0; p < 8; ++p) {
                half2v t = pkfma(c2, B2[p], C2[p]);
                t = pkfma(e2, A2[p], t);
                t = __builtin_elementwise_max(t, zero2);  // v_pk_max_f16
                o0 = __builtin_amdgcn_fdot2(t, U0_2[p], o0, false);
                o1 = __builtin_amdgcn_fdot2(t, U1_2[p], o1, false);
                o2 = __builtin_amdgcn_fdot2(t, U2_2[p], o2, false);
            }

            cacc = fmaf(o0, rd, cacc);
            const float sr  = o1 * rd;
            const float sr2 = sr * sr;
            const float sr6 = sr2 * sr2 * sr2;
            ljacc = fmaf(o2, fmaf(sr6, sr6, -sr6), ljacc);
        }
    }

    // Deterministic in-block reduction: wave shuffle, then LDS across waves.
#pragma unroll
    for (int off = 32; off > 0; off >>= 1) {
        cacc  += __shfl_down(cacc, off, 64);
        ljacc += __shfl_down(ljacc, off, 64);
    }
    __shared__ float s_c[THREADS / 64], s_l[THREADS / 64];
    const int wave = threadIdx.x >> 6;
    const int lane = threadIdx.x & 63;
    if (lane == 0) { s_c[wave] = cacc; s_l[wave] = ljacc; }
    __syncthreads();
    if (threadIdx.x == 0) {
        float ct = 0.0f, lt = 0.0f;
#pragma unroll
        for (int w = 0; w < THREADS / 64; ++w) { ct += s_c[w]; lt += s_l[w]; }
        partials[2 * blockIdx.x + 0] = ct;
        partials[2 * blockIdx.x + 1] = lt;
    }
}

// Final reduction over block partials (fixed order -> deterministic).
__global__ __launch_bounds__(PTHREADS, 1) void energy_reduce_kernel(
    const float* __restrict__ partials, int nblocks,
    const float* __restrict__ bias, float* __restrict__ out)
{
    float ct = 0.0f, lt = 0.0f;
    for (int b = threadIdx.x; b < nblocks; b += PTHREADS) {
        ct += partials[2 * b + 0];
        lt += partials[2 * b + 1];
    }
#pragma unroll
    for (int off = 32; off > 0; off >>= 1) {
        ct += __shfl_down(ct, off, 64);
        lt += __shfl_down(lt, off, 64);
    }
    __shared__ float s_c[PTHREADS / 64], s_l[PTHREADS / 64];
    const int wave = threadIdx.x >> 6;
    const int lane = threadIdx.x & 63;
    if (lane == 0) { s_c[wave] = ct; s_l[wave] = lt; }
    __syncthreads();
    if (threadIdx.x == 0) {
        float c = 0.0f, l = 0.0f;
#pragma unroll
        for (int w = 0; w < PTHREADS / 64; ++w) { c += s_c[w]; l += s_l[w]; }
        // COULOMB_CONSTANT = -1, EV = 1.602e-19
        out[0] = -c + 1.602e-19f * l + bias[0];
    }
}

extern "C" void kernel_launch(void* const* d_in, const int* in_sizes, int n_in,
                              void* d_out, int out_size, void* d_ws, size_t ws_size,
                              hipStream_t stream)
{
    const float* coords  = (const float*)d_in[0];
    const int*   atom_ix = (const int*)d_in[1];
    const float* charges = (const float*)d_in[2];
    const float* emb     = (const float*)d_in[3];
    const float* W1      = (const float*)d_in[4];
    const float* b1      = (const float*)d_in[5];
    const float* W2      = (const float*)d_in[6];
    const float* b2      = (const float*)d_in[7];
    const float* bias    = (const float*)d_in[8];

    float*  out      = (float*)d_out;
    float*  partials = (float*)d_ws;
    float4* pack     = (float4*)((char*)d_ws + PACK_OFF);

    const int n       = in_sizes[1];                       // 4096 atoms
    const int nblocks = (n / ROWS_PER_BLOCK) * JSPLIT;     // 1024 blocks

    pack_kernel<<<(n + PTHREADS - 1) / PTHREADS, PTHREADS, 0, stream>>>(
        coords, charges, pack, n);
    energy_main_kernel<<<nblocks, THREADS, 0, stream>>>(
        pack, atom_ix, emb, W1, b1, W2, b2, partials, n);
    energy_reduce_kernel<<<1, PTHREADS, 0, stream>>>(partials, nblocks, bias, out);
}

// Round 12
// 67.567 us; speedup vs baseline: 3.2356x; 3.2356x over previous
//
#include <hip/hip_runtime.h>
#include <hip/hip_bf16.h>
#include <stdint.h>

#define THREADS 256
#define WAVES (THREADS / 64)
#define ROWS_PER_BLOCK 8
#define JSPLIT 2
#define EMB_ROWS 5050
#define PACK_OFF 65536   // byte offset of packed float4 array in d_ws

typedef __fp16 fp16x2 __attribute__((ext_vector_type(2)));
typedef __fp16 half4  __attribute__((ext_vector_type(4)));
typedef float  floatx4 __attribute__((ext_vector_type(4)));
typedef unsigned int uint2v __attribute__((ext_vector_type(2)));

__device__ __forceinline__ fp16x2 pkrtz(float a, float b) {
    return __builtin_amdgcn_cvt_pkrtz(a, b);     // v_cvt_pkrtz_f16_f32
}
__device__ __forceinline__ float bpermf(int idx_bytes, float v) {
    return __builtin_bit_cast(float,
        __builtin_amdgcn_ds_bpermute(idx_bytes, __builtin_bit_cast(int, v)));
}

__global__ __launch_bounds__(THREADS) void pack_kernel(
    const float* __restrict__ coords, const float* __restrict__ charges,
    float4* __restrict__ pack, int n)
{
    const int i = blockIdx.x * THREADS + threadIdx.x;
    if (i < n)
        pack[i] = make_float4(coords[3 * i], coords[3 * i + 1],
                              coords[3 * i + 2], charges[i]);
}

// MLP on the matrix pipe. Per 16-pair sub-round:
//   MFMA1: z[h][p] = W1f * (e,c) + b1   (16x16x16 f16, C-in = bias)
//   in-lane relu + cvt (D1 layout == MFMA2 B layout)
//   MFMA2: o[m][p] = W2f * relu(z) + b2
// Then bpermute o-triples back to pair-per-lane for the f32 epilogue.
__global__ __launch_bounds__(THREADS) void energy_main_kernel(
    const float4* __restrict__ pack,
    const int*    __restrict__ atom_ix,
    const float*  __restrict__ emb,
    const float*  __restrict__ W1,
    const float*  __restrict__ b1,
    const float*  __restrict__ W2,
    const float*  __restrict__ b2,
    float* __restrict__ partials,
    int n_atoms)
{
    __shared__ float s_emb[EMB_ROWS];
    for (int t = threadIdx.x; t < EMB_ROWS; t += THREADS) s_emb[t] = emb[t];

    const int lane  = threadIdx.x & 63;
    const int g     = lane >> 4;      // 4-lane-group index (k-block / row-block)
    const int row16 = lane & 15;

    // A1 fragment: A1[row=hidden][k] ; k=0 -> W1[0][row], k=1 -> W1[1][row].
    half4 A1 = (half4)(__fp16)0;
    if (g == 0) {
        const fp16x2 t = pkrtz(W1[row16], W1[16 + row16]);
        A1[0] = t[0]; A1[1] = t[1];
    }
    // A2 fragment: A2[row=out][k=hidden] = W2[3*hidden + out], out<3.
    half4 A2 = (half4)(__fp16)0;
    if (row16 < 3) {
#pragma unroll
        for (int e = 0; e < 4; ++e)
            A2[e] = (__fp16)W2[3 * (4 * g + e) + row16];
    }
    // C-in fragments (bias via accumulator): C[row][*] broadcast along pairs.
    floatx4 C1;
#pragma unroll
    for (int q = 0; q < 4; ++q) C1[q] = b1[4 * g + q];
    floatx4 C2 = {0.f, 0.f, 0.f, 0.f};
    if (g == 0) { C2[0] = b2[0]; C2[1] = b2[1]; C2[2] = b2[2]; }

    const int rb   = blockIdx.x / JSPLIT;
    const int js   = blockIdx.x % JSPLIT;
    const int row0 = rb * ROWS_PER_BLOCK;
    const int jlen = n_atoms / JSPLIT;
    const int wv   = threadIdx.x >> 6;
    const int jw   = jlen / WAVES;                 // j's per wave (512)
    const int j0   = js * jlen + wv * jw;

    float xr[ROWS_PER_BLOCK], yr[ROWS_PER_BLOCK], zr[ROWS_PER_BLOCK], qr[ROWS_PER_BLOCK];
    int   br[ROWS_PER_BLOCK];
#pragma unroll
    for (int r = 0; r < ROWS_PER_BLOCK; ++r) {
        const int i = row0 + r;
        const float4 p = pack[i];
        xr[r] = p.x; yr[r] = p.y; zr[r] = p.z; qr[r] = p.w;
        const int a = atom_ix[i];
        br[r] = (a * (a + 1)) >> 1;
    }
    __syncthreads();

    float cacc = 0.0f, ljacc = 0.0f;

#pragma unroll 1
    for (int jr = 0; jr < jw; jr += 64) {
        const int j = j0 + jr + lane;
        const float4 pj = pack[j];
        const int    aj = atom_ix[j];

#pragma unroll
        for (int r = 0; r < ROWS_PER_BLOCK; ++r) {
            const float dx = pj.x - xr[r];
            const float dy = pj.y - yr[r];
            const float dz = pj.z - zr[r];
            const float sq = fmaf(dx, dx, fmaf(dy, dy, dz * dz));
            // diagonal: v_rsq_f32(0)=+inf, fminf(inf,10)=10 == reference clamp
            const float rd = fminf(__builtin_amdgcn_rsqf(sq), 10.0f);

            const float e = s_emb[br[r] + aj];
            const float c = qr[r] * pj.w;
            const float pkec = __builtin_bit_cast(float, pkrtz(e, c));

            floatx4 d2s[4];
#pragma unroll
            for (int s = 0; s < 4; ++s) {
                // stage (e,c) of pairs s*16..s*16+15 into cols of lanes 0..15
                float bs = bpermf(((s << 4) | row16) << 2, pkec);
                const unsigned bu = (g == 0) ? __builtin_bit_cast(unsigned, bs) : 0u;
                const half4 B1 = __builtin_bit_cast(half4, (uint2v){bu, 0u});
                const floatx4 d1 =
                    __builtin_amdgcn_mfma_f32_16x16x16f16(A1, B1, C1, 0, 0, 0);
                const fp16x2 h01 = pkrtz(fmaxf(d1[0], 0.f), fmaxf(d1[1], 0.f));
                const fp16x2 h23 = pkrtz(fmaxf(d1[2], 0.f), fmaxf(d1[3], 0.f));
                const half4 B2 = {h01[0], h01[1], h23[0], h23[1]};
                d2s[s] = __builtin_amdgcn_mfma_f32_16x16x16f16(A2, B2, C2, 0, 0, 0);
            }

            // redistribute o_m(pair p) -> lane p  (source lanes 0..15, reg m)
            float o[3];
#pragma unroll
            for (int m = 0; m < 3; ++m) {
                const int idx = row16 << 2;
                const float t0 = bpermf(idx, d2s[0][m]);
                const float t1 = bpermf(idx, d2s[1][m]);
                const float t2 = bpermf(idx, d2s[2][m]);
                const float t3 = bpermf(idx, d2s[3][m]);
                o[m] = (g == 0) ? t0 : (g == 1) ? t1 : (g == 2) ? t2 : t3;
            }

            cacc = fmaf(o[0], rd, cacc);
            const float sr  = o[1] * rd;
            const float sr2 = sr * sr;
            const float sr6 = sr2 * sr2 * sr2;
            ljacc = fmaf(o[2], fmaf(sr6, sr6, -sr6), ljacc);
        }
    }

    // Deterministic in-block reduction: wave shuffle, then LDS across waves.
#pragma unroll
    for (int off = 32; off > 0; off >>= 1) {
        cacc  += __shfl_down(cacc, off, 64);
        ljacc += __shfl_down(ljacc, off, 64);
    }
    __shared__ float s_c[WAVES], s_l[WAVES];
    if (lane == 0) { s_c[wv] = cacc; s_l[wv] = ljacc; }
    __syncthreads();
    if (threadIdx.x == 0) {
        float ct = 0.0f, lt = 0.0f;
#pragma unroll
        for (int w = 0; w < WAVES; ++w) { ct += s_c[w]; lt += s_l[w]; }
        partials[2 * blockIdx.x + 0] = ct;
        partials[2 * blockIdx.x + 1] = lt;
    }
}

// Final reduction over block partials (fixed order -> deterministic).
__global__ __launch_bounds__(THREADS, 1) void energy_reduce_kernel(
    const float* __restrict__ partials, int nblocks,
    const float* __restrict__ bias, float* __restrict__ out)
{
    float ct = 0.0f, lt = 0.0f;
    for (int b = threadIdx.x; b < nblocks; b += THREADS) {
        ct += partials[2 * b + 0];
        lt += partials[2 * b + 1];
    }
#pragma unroll
    for (int off = 32; off > 0; off >>= 1) {
        ct += __shfl_down(ct, off, 64);
        lt += __shfl_down(lt, off, 64);
    }
    __shared__ float s_c[THREADS / 64], s_l[THREADS / 64];
    const int wave = threadIdx.x >> 6;
    const int lane = threadIdx.x & 63;
    if (lane == 0) { s_c[wave] = ct; s_l[wave] = lt; }
    __syncthreads();
    if (threadIdx.x == 0) {
        float c = 0.0f, l = 0.0f;
#pragma unroll
        for (int w = 0; w < THREADS / 64; ++w) { c += s_c[w]; l += s_l[w]; }
        // COULOMB_CONSTANT = -1, EV = 1.602e-19
        out[0] = -c + 1.602e-19f * l + bias[0];
    }
}

extern "C" void kernel_launch(void* const* d_in, const int* in_sizes, int n_in,
                              void* d_out, int out_size, void* d_ws, size_t ws_size,
                              hipStream_t stream)
{
    const float* coords  = (const float*)d_in[0];
    const int*   atom_ix = (const int*)d_in[1];
    const float* charges = (const float*)d_in[2];
    const float* emb     = (const float*)d_in[3];
    const float* W1      = (const float*)d_in[4];
    const float* b1      = (const float*)d_in[5];
    const float* W2      = (const float*)d_in[6];
    const float* b2      = (const float*)d_in[7];
    const float* bias    = (const float*)d_in[8];

    float*  out      = (float*)d_out;
    float*  partials = (float*)d_ws;
    float4* pack     = (float4*)((char*)d_ws + PACK_OFF);

    const int n       = in_sizes[1];                       // 4096 atoms
    const int nblocks = (n / ROWS_PER_BLOCK) * JSPLIT;     // 1024 blocks

    pack_kernel<<<(n + THREADS - 1) / THREADS, THREADS, 0, stream>>>(
        coords, charges, pack, n);
    energy_main_kernel<<<nblocks, THREADS, 0, stream>>>(
        pack, atom_ix, emb, W1, b1, W2, b2, partials, n);
    energy_reduce_kernel<<<1, THREADS, 0, stream>>>(partials, nblocks, bias, out);
}